// Round 5
// baseline (776.235 us; speedup 1.0000x reference)
//
#include <hip/hip_runtime.h>

typedef unsigned short u16;
typedef _Float16 f16;
typedef __attribute__((ext_vector_type(8))) _Float16 f16x8;   // MFMA A/B operand (4 VGPRs)
typedef __attribute__((ext_vector_type(4))) float f32x4;

#define MFMA16(acc, a, b) acc = __builtin_amdgcn_mfma_f32_16x16x32_f16(a, b, acc, 0, 0, 0)

__device__ __forceinline__ void gl2lds16(const void* g, void* l) {
  __builtin_amdgcn_global_load_lds(
      (const __attribute__((address_space(1))) void*)g,
      (__attribute__((address_space(3))) void*)l, 16, 0, 0);
}

// ---------------------------------------------------------------------------
// f32 -> f16 conversion, 8 elems/thread, vectorized.
// ---------------------------------------------------------------------------
__global__ __launch_bounds__(256) void cvt_f32_f16_k(const float* __restrict__ src, f16* __restrict__ dst,
                                                     int n8) {
  int i = blockIdx.x * 256 + threadIdx.x;
  if (i >= n8) return;
  const float* p = src + (size_t)i * 8;
  f32x4 a = *(const f32x4*)p;
  f32x4 b = *(const f32x4*)(p + 4);
  f16x8 o;
#pragma unroll
  for (int j = 0; j < 4; j++) {
    o[j] = (f16)a[j];
    o[j + 4] = (f16)b[j];
  }
  *(f16x8*)(dst + (size_t)i * 8) = o;
}

// ---------------------------------------------------------------------------
// GEMM: C[M,N] = A[M,K] @ W[N,K]^T + bias[N]; f16 in, f32 accum. (m97 structure)
// EPI 0: f32 out[row*N+col]   (final output)
// EPI 1: f16 out[((row>>10)*16 + (col>>6))*65536 + (row&1023)*64 + (col&63)]  ([B,H,L,64])
// ---------------------------------------------------------------------------
template <int EPI>
__global__ __launch_bounds__(256) void gemm_bt(const f16* __restrict__ A, const f16* __restrict__ Wt,
                                               const float* __restrict__ bias, void* __restrict__ outv,
                                               int M, int N, int K, float scale) {
  const int nbn = N >> 7;
  int id = blockIdx.x;
  int m0 = (id / nbn) << 7;
  int n0 = (id % nbn) << 7;
  int tid = threadIdx.x;
  int w = tid >> 6, lane = tid & 63, c = lane & 15, g = lane >> 4;
  int wm = (w >> 1) << 6, wn = (w & 1) << 6;

  __shared__ f16 As[128 * 32];
  __shared__ f16 Bs[128 * 32];

  f32x4 acc[4][4] = {};
  int ci0 = tid, ci1 = tid + 256;

  for (int k0 = 0; k0 < K; k0 += 32) {
    __syncthreads();
    gl2lds16(A + (size_t)(m0 + (ci0 >> 2)) * K + k0 + ((ci0 & 3) << 3), As + w * 512);
    gl2lds16(A + (size_t)(m0 + (ci1 >> 2)) * K + k0 + ((ci1 & 3) << 3), As + w * 512 + 2048);
    gl2lds16(Wt + (size_t)(n0 + (ci0 >> 2)) * K + k0 + ((ci0 & 3) << 3), Bs + w * 512);
    gl2lds16(Wt + (size_t)(n0 + (ci1 >> 2)) * K + k0 + ((ci1 & 3) << 3), Bs + w * 512 + 2048);
    __syncthreads();
    f16x8 af[4], bf[4];
#pragma unroll
    for (int mf = 0; mf < 4; mf++) af[mf] = *(const f16x8*)(As + ((wm + mf * 16 + c) << 5) + (g << 3));
#pragma unroll
    for (int nf = 0; nf < 4; nf++) bf[nf] = *(const f16x8*)(Bs + ((wn + nf * 16 + c) << 5) + (g << 3));
#pragma unroll
    for (int mf = 0; mf < 4; mf++)
#pragma unroll
      for (int nf = 0; nf < 4; nf++) MFMA16(acc[mf][nf], af[mf], bf[nf]);
  }

#pragma unroll
  for (int mf = 0; mf < 4; mf++)
#pragma unroll
    for (int nf = 0; nf < 4; nf++)
#pragma unroll
      for (int r = 0; r < 4; r++) {
        int row = m0 + wm + mf * 16 + (g << 2) + r;
        int col = n0 + wn + nf * 16 + c;
        float v = (acc[mf][nf][r] + bias[col]) * scale;
        if (EPI == 0) {
          ((float*)outv)[(size_t)row * N + col] = v;
        } else {
          size_t idx = (size_t)((row >> 10) * 16 + (col >> 6)) * 65536 + ((row & 1023) << 6) + (col & 63);
          ((u16*)outv)[idx] = __builtin_bit_cast(u16, (f16)v);
        }
      }
}

// ---------------------------------------------------------------------------
// FUSED scores + softmax + attn-write + PV + rel-values -> ctx.
// One block per (b,h, 16-row q-tile); 4 waves, each owns a 256-wide k-chunk
// for scores and a 16-wide d-slice for PV. Full P row-block kept in LDS
// (f16, XOR-swizzled); V^T staged in 128-k slices.
// ---------------------------------------------------------------------------
__global__ __launch_bounds__(256) void attn_fused(const f16* __restrict__ Q, const f16* __restrict__ Km,
                                                  const f16* __restrict__ V, const f16* __restrict__ rel,
                                                  float* __restrict__ attn, f16* __restrict__ ctx) {
  int id = blockIdx.x;
  int sw = ((id & 7) << 10) + (id >> 3);  // XCD-bijective swizzle (8192 % 8 == 0)
  int bh = sw >> 6;
  int q0 = (sw & 63) << 4;
  int b = bh >> 4, h = bh & 15;
  int tid = threadIdx.x;
  int w = tid >> 6, lane = tid & 63, c = lane & 15, g = lane >> 4;

  __shared__ float qrel_s[16 * 68];
  __shared__ float rmax[4][16], rsum[4][16], rlo[4][16], rhi[4][16];
  __shared__ float lo_s[16], hi_s[16];
  __shared__ f16 P_lds[16 * 1024];  // [row][k], byte addr: row*2048 + ((k*2) ^ ((row&7)<<4))
  __shared__ f16 VT[64][136];       // V^T slice [d][k_local], 272 B row stride
  __shared__ f16 rel_s[65 * 64];

  const f16* Qb = Q + ((size_t)bh << 16);
  const f16* Kb = Km + ((size_t)bh << 16);
  const f16* Vb = V + ((size_t)bh << 16);

  for (int i = tid; i < 65 * 64; i += 256) rel_s[i] = rel[i];

  f16x8 aq0 = *(const f16x8*)(Qb + ((q0 + c) << 6) + (g << 3));
  f16x8 aq1 = *(const f16x8*)(Qb + ((q0 + c) << 6) + 32 + (g << 3));

  if (w == 0) {  // qrel[q,t] = Q[q,:] . rel_emb[t,:]
#pragma unroll
    for (int tf = 0; tf < 5; tf++) {
      int t = tf * 16 + c;
      int tc = (t < 65) ? t : 0;
      f32x4 ar = {};
      f16x8 b0 = *(const f16x8*)(rel + (tc << 6) + (g << 3));
      f16x8 b1 = *(const f16x8*)(rel + (tc << 6) + 32 + (g << 3));
      MFMA16(ar, aq0, b0);
      MFMA16(ar, aq1, b1);
      if (t < 65) {
#pragma unroll
        for (int r = 0; r < 4; r++) qrel_s[((g << 2) + r) * 68 + t] = ar[r];
      }
    }
  }
  __syncthreads();

  float s[16][4];
  int kbase = w << 8;
#pragma unroll
  for (int f = 0; f < 16; f++) {
    int kcol = kbase + (f << 4) + c;
    f32x4 a4 = {};
    f16x8 b0 = *(const f16x8*)(Kb + (kcol << 6) + (g << 3));
    f16x8 b1 = *(const f16x8*)(Kb + (kcol << 6) + 32 + (g << 3));
    MFMA16(a4, aq0, b0);
    MFMA16(a4, aq1, b1);
#pragma unroll
    for (int r = 0; r < 4; r++) {
      int rowl = (g << 2) + r;
      int d = kcol - (q0 + rowl);
      int t = (d < -32 ? -32 : (d > 32 ? 32 : d)) + 32;
      s[f][r] = a4[r] + qrel_s[rowl * 68 + t];
    }
  }

  float m[4] = {-3.0e38f, -3.0e38f, -3.0e38f, -3.0e38f};
#pragma unroll
  for (int f = 0; f < 16; f++)
#pragma unroll
    for (int r = 0; r < 4; r++) m[r] = fmaxf(m[r], s[f][r]);
#pragma unroll
  for (int mk = 1; mk <= 8; mk <<= 1)
#pragma unroll
    for (int r = 0; r < 4; r++) m[r] = fmaxf(m[r], __shfl_xor(m[r], mk, 64));
  if (c == 0) {
#pragma unroll
    for (int r = 0; r < 4; r++) rmax[w][(g << 2) + r] = m[r];
  }
  __syncthreads();
  float gm[4];
#pragma unroll
  for (int r = 0; r < 4; r++) {
    int rowl = (g << 2) + r;
    gm[r] = fmaxf(fmaxf(rmax[0][rowl], rmax[1][rowl]), fmaxf(rmax[2][rowl], rmax[3][rowl]));
  }
  float sum[4] = {0, 0, 0, 0}, lo[4] = {0, 0, 0, 0}, hi[4] = {0, 0, 0, 0};
#pragma unroll
  for (int f = 0; f < 16; f++)
#pragma unroll
    for (int r = 0; r < 4; r++) {
      float p = __expf(s[f][r] - gm[r]);
      s[f][r] = p;
      sum[r] += p;
      int d = (kbase + (f << 4) + c) - (q0 + (g << 2) + r);
      if (d <= -32) lo[r] += p;
      if (d >= 32) hi[r] += p;
    }
#pragma unroll
  for (int mk = 1; mk <= 8; mk <<= 1)
#pragma unroll
    for (int r = 0; r < 4; r++) {
      sum[r] += __shfl_xor(sum[r], mk, 64);
      lo[r] += __shfl_xor(lo[r], mk, 64);
      hi[r] += __shfl_xor(hi[r], mk, 64);
    }
  if (c == 0) {
#pragma unroll
    for (int r = 0; r < 4; r++) {
      int rowl = (g << 2) + r;
      rsum[w][rowl] = sum[r];
      rlo[w][rowl] = lo[r];
      rhi[w][rowl] = hi[r];
    }
  }
  __syncthreads();
  float inv[4];
#pragma unroll
  for (int r = 0; r < 4; r++) {
    int rowl = (g << 2) + r;
    float tot = rsum[0][rowl] + rsum[1][rowl] + rsum[2][rowl] + rsum[3][rowl];
    inv[r] = 1.0f / tot;
  }
  if (w == 0 && c == 0) {
#pragma unroll
    for (int r = 0; r < 4; r++) {
      int rowl = (g << 2) + r;
      float l4 = rlo[0][rowl] + rlo[1][rowl] + rlo[2][rowl] + rlo[3][rowl];
      float h4 = rhi[0][rowl] + rhi[1][rowl] + rhi[2][rowl] + rhi[3][rowl];
      lo_s[rowl] = l4 * inv[r];
      hi_s[rowl] = h4 * inv[r];
    }
  }

  // write attn (f32, required output) + P into LDS (normalized f16, swizzled)
  float* ab = attn + ((size_t)bh << 20);
#pragma unroll
  for (int f = 0; f < 16; f++)
#pragma unroll
    for (int r = 0; r < 4; r++) {
      int rowl = (g << 2) + r;
      int k = kbase + (f << 4) + c;
      float p = s[f][r] * inv[r];
      ab[((size_t)(q0 + rowl) << 10) | (size_t)k] = p;
      int off = (rowl << 11) + ((k << 1) ^ ((rowl & 7) << 4));
      *(f16*)((char*)P_lds + off) = (f16)p;
    }
  __syncthreads();

  // PV: wave w owns d-slice [16w, 16w+16); full K=1024 via 128-k V^T slices.
  f32x4 pv0 = {}, pv1 = {};
  for (int k0 = 0; k0 < 1024; k0 += 128) {
    if (k0) __syncthreads();
    {
      int kk = tid & 127;
      int dh = (tid >> 7) << 5;
      const f16* vp = Vb + ((size_t)(k0 + kk) << 6) + dh;
#pragma unroll
      for (int s4 = 0; s4 < 4; s4++) {
        f16x8 vv = *(const f16x8*)(vp + s4 * 8);
#pragma unroll
        for (int j = 0; j < 8; j++) VT[dh + s4 * 8 + j][kk] = vv[j];
      }
    }
    __syncthreads();
#pragma unroll
    for (int kk = 0; kk < 128; kk += 64) {
      f16x8 aP0 = *(const f16x8*)((char*)P_lds + (c << 11) + (((k0 + kk + (g << 3)) << 1) ^ ((c & 7) << 4)));
      f16x8 bV0 = *(const f16x8*)(&VT[(w << 4) + c][kk + (g << 3)]);
      MFMA16(pv0, aP0, bV0);
      f16x8 aP1 = *(const f16x8*)((char*)P_lds + (c << 11) + (((k0 + kk + 32 + (g << 3)) << 1) ^ ((c & 7) << 4)));
      f16x8 bV1 = *(const f16x8*)(&VT[(w << 4) + c][kk + 32 + (g << 3)]);
      MFMA16(pv1, aP1, bV1);
    }
  }

  // rel-value epilogue: buckets (t=0/64) + diagonal band (t=1..63) from P_lds.
  int d = (w << 4) + c;
  float cval[4];
#pragma unroll
  for (int r = 0; r < 4; r++) {
    int rowl = (g << 2) + r;
    cval[r] = pv0[r] + pv1[r] + lo_s[rowl] * (float)rel_s[d] + hi_s[rowl] * (float)rel_s[64 * 64 + d];
  }
  for (int t = 1; t < 64; t++) {
    float rv = (float)rel_s[t * 64 + d];
#pragma unroll
    for (int r = 0; r < 4; r++) {
      int rowl = (g << 2) + r;
      int k = q0 + rowl + t - 32;
      if (k >= 0 && k < 1024) {
        f16 pk = *(const f16*)((char*)P_lds + (rowl << 11) + ((k << 1) ^ ((rowl & 7) << 4)));
        cval[r] += (float)pk * rv;
      }
    }
  }

#pragma unroll
  for (int r = 0; r < 4; r++) {
    int rowl = (g << 2) + r;
    ctx[(((size_t)(b << 10) + (size_t)(q0 + rowl)) << 10) + (h << 6) + d] = (f16)cval[r];
  }
}

extern "C" void kernel_launch(void* const* d_in, const int* in_sizes, int n_in, void* d_out, int out_size,
                              void* d_ws, size_t ws_size, hipStream_t stream) {
  const float* key = (const float*)d_in[0];
  const float* value = (const float*)d_in[1];
  const float* query = (const float*)d_in[2];
  const float* Wq = (const float*)d_in[3];
  const float* bq = (const float*)d_in[4];
  const float* Wk = (const float*)d_in[5];
  const float* bk = (const float*)d_in[6];
  const float* Wv = (const float*)d_in[7];
  const float* bv = (const float*)d_in[8];
  const float* Wo = (const float*)d_in[9];
  const float* bo = (const float*)d_in[10];
  const float* rel = (const float*)d_in[11];

  char* ws = (char*)d_ws;
  f16* Xf = (f16*)(ws);                  // 16 MB: f16 input staging (q/k/v); later ctx [B,L,D]
  f16* Qw = (f16*)(ws + (16u << 20));    // 16 MB: Q proj [B,H,L,64]
  f16* Kw = (f16*)(ws + (32u << 20));    // 16 MB: K proj
  f16* Vw = (f16*)(ws + (48u << 20));    // 16 MB: V proj
  f16* Wf = (f16*)(ws + (64u << 20));    // 2 MB: shared weight staging (serialized by stream order)
  f16* relf = (f16*)(ws + (66u << 20));  // 8320 B
  // peak ws use: ~66.1 MB

  float* outp = (float*)d_out;
  float* attnp = outp + (size_t)8 * 1024 * 1024;  // attn (f32) starts at elem 8388608

  dim3 blk(256);
  const int n8x = (8 * 1024 * 1024) / 8;
  const int n8w = (1024 * 1024) / 8;
  const int n8r = (65 * 64) / 8;

  cvt_f32_f16_k<<<(n8r + 255) / 256, blk, 0, stream>>>(rel, relf, n8r);

  cvt_f32_f16_k<<<n8w / 256, blk, 0, stream>>>(Wq, Wf, n8w);
  cvt_f32_f16_k<<<n8x / 256, blk, 0, stream>>>(query, Xf, n8x);
  gemm_bt<1><<<512, blk, 0, stream>>>(Xf, Wf, bq, Qw, 8192, 1024, 1024, 0.125f);

  cvt_f32_f16_k<<<n8w / 256, blk, 0, stream>>>(Wk, Wf, n8w);
  cvt_f32_f16_k<<<n8x / 256, blk, 0, stream>>>(key, Xf, n8x);
  gemm_bt<1><<<512, blk, 0, stream>>>(Xf, Wf, bk, Kw, 8192, 1024, 1024, 1.0f);

  cvt_f32_f16_k<<<n8w / 256, blk, 0, stream>>>(Wv, Wf, n8w);
  cvt_f32_f16_k<<<n8x / 256, blk, 0, stream>>>(value, Xf, n8x);
  gemm_bt<1><<<512, blk, 0, stream>>>(Xf, Wf, bv, Vw, 8192, 1024, 1024, 1.0f);

  attn_fused<<<8192, blk, 0, stream>>>(Qw, Kw, Vw, relf, attnp, Xf);  // ctx -> Xf (free after V cvt)

  cvt_f32_f16_k<<<n8w / 256, blk, 0, stream>>>(Wo, Wf, n8w);
  gemm_bt<0><<<512, blk, 0, stream>>>(Xf, Wf, bo, outp, 8192, 1024, 1024, 1.0f);
}

// Round 6
// 507.277 us; speedup vs baseline: 1.5302x; 1.5302x over previous
//
#include <hip/hip_runtime.h>

typedef unsigned short u16;
typedef _Float16 f16;
typedef __attribute__((ext_vector_type(8))) _Float16 f16x8;   // MFMA A/B operand (4 VGPRs)
typedef __attribute__((ext_vector_type(4))) _Float16 f16x4;
typedef __attribute__((ext_vector_type(2))) _Float16 f16x2;
typedef __attribute__((ext_vector_type(4))) float f32x4;

#define MFMA16(acc, a, b) acc = __builtin_amdgcn_mfma_f32_16x16x32_f16(a, b, acc, 0, 0, 0)

__device__ __forceinline__ void gl2lds16(const void* g, void* l) {
  __builtin_amdgcn_global_load_lds(
      (const __attribute__((address_space(1))) void*)g,
      (__attribute__((address_space(3))) void*)l, 16, 0, 0);
}

// ---------------------------------------------------------------------------
// f32 -> f16 conversion, 8 elems/thread, vectorized.
// ---------------------------------------------------------------------------
__global__ __launch_bounds__(256) void cvt_f32_f16_k(const float* __restrict__ src, f16* __restrict__ dst,
                                                     int n8) {
  int i = blockIdx.x * 256 + threadIdx.x;
  if (i >= n8) return;
  const float* p = src + (size_t)i * 8;
  f32x4 a = *(const f32x4*)p;
  f32x4 b = *(const f32x4*)(p + 4);
  f16x8 o;
#pragma unroll
  for (int j = 0; j < 4; j++) {
    o[j] = (f16)a[j];
    o[j + 4] = (f16)b[j];
  }
  *(f16x8*)(dst + (size_t)i * 8) = o;
}

// ---------------------------------------------------------------------------
// GEMM: C[M,N] = A[M,K] @ W[N,K]^T + bias[N]; f16 in, f32 accum. (m97 structure)
// EPI 0: f32 out[row*N+col]   (final output)
// EPI 1: f16 out[bh*65536 + (row&1023)*64 + (col&63)]   ([B,H,L,64])
// EPI 2: f16 out[bh*65536 + (col&63)*1024 + (row&1023)] ([B,H,64,L] = V^T)
// ---------------------------------------------------------------------------
template <int EPI>
__global__ __launch_bounds__(256) void gemm_bt(const f16* __restrict__ A, const f16* __restrict__ Wt,
                                               const float* __restrict__ bias, void* __restrict__ outv,
                                               int M, int N, int K, float scale) {
  const int nbn = N >> 7;
  int id = blockIdx.x;
  int m0 = (id / nbn) << 7;
  int n0 = (id % nbn) << 7;
  int tid = threadIdx.x;
  int w = tid >> 6, lane = tid & 63, c = lane & 15, g = lane >> 4;
  int wm = (w >> 1) << 6, wn = (w & 1) << 6;

  __shared__ f16 As[128 * 32];
  __shared__ f16 Bs[128 * 32];

  f32x4 acc[4][4] = {};
  int ci0 = tid, ci1 = tid + 256;

  for (int k0 = 0; k0 < K; k0 += 32) {
    __syncthreads();
    gl2lds16(A + (size_t)(m0 + (ci0 >> 2)) * K + k0 + ((ci0 & 3) << 3), As + w * 512);
    gl2lds16(A + (size_t)(m0 + (ci1 >> 2)) * K + k0 + ((ci1 & 3) << 3), As + w * 512 + 2048);
    gl2lds16(Wt + (size_t)(n0 + (ci0 >> 2)) * K + k0 + ((ci0 & 3) << 3), Bs + w * 512);
    gl2lds16(Wt + (size_t)(n0 + (ci1 >> 2)) * K + k0 + ((ci1 & 3) << 3), Bs + w * 512 + 2048);
    __syncthreads();
    f16x8 af[4], bf[4];
#pragma unroll
    for (int mf = 0; mf < 4; mf++) af[mf] = *(const f16x8*)(As + ((wm + mf * 16 + c) << 5) + (g << 3));
#pragma unroll
    for (int nf = 0; nf < 4; nf++) bf[nf] = *(const f16x8*)(Bs + ((wn + nf * 16 + c) << 5) + (g << 3));
#pragma unroll
    for (int mf = 0; mf < 4; mf++)
#pragma unroll
      for (int nf = 0; nf < 4; nf++) MFMA16(acc[mf][nf], af[mf], bf[nf]);
  }

#pragma unroll
  for (int mf = 0; mf < 4; mf++)
#pragma unroll
    for (int nf = 0; nf < 4; nf++) {
      if (EPI == 2) {
        int row0 = m0 + wm + mf * 16 + (g << 2);
        int col = n0 + wn + nf * 16 + c;
        f16x4 vv;
#pragma unroll
        for (int r = 0; r < 4; r++) vv[r] = (f16)((acc[mf][nf][r] + bias[col]) * scale);
        size_t idx = (size_t)((row0 >> 10) * 16 + (col >> 6)) * 65536 + (size_t)(col & 63) * 1024 + (row0 & 1023);
        *(f16x4*)((f16*)outv + idx) = vv;
      } else {
#pragma unroll
        for (int r = 0; r < 4; r++) {
          int row = m0 + wm + mf * 16 + (g << 2) + r;
          int col = n0 + wn + nf * 16 + c;
          float v = (acc[mf][nf][r] + bias[col]) * scale;
          if (EPI == 0) {
            ((float*)outv)[(size_t)row * N + col] = v;
          } else {
            size_t idx = (size_t)((row >> 10) * 16 + (col >> 6)) * 65536 + ((row & 1023) << 6) + (col & 63);
            ((f16*)outv)[idx] = (f16)v;
          }
        }
      }
    }
}

// ---------------------------------------------------------------------------
// FUSED scores + softmax + attn-write + PV + rel-values -> ctx.
// Block = (b,h, 16 q-rows); 4 waves own 256-wide k-chunks for scores.
// P transposed through k-major LDS [k][q] (stride 18). PV computed as
// ctx^T = V^T @ P^T with V^T fragments loaded DIRECTLY from global (L2-hot,
// pre-transposed by the V-projection GEMM). One barrier in the whole PV path.
// ---------------------------------------------------------------------------
__global__ __launch_bounds__(256) void attn_fused(const f16* __restrict__ Q, const f16* __restrict__ Km,
                                                  const f16* __restrict__ Vt, const f16* __restrict__ rel,
                                                  float* __restrict__ attn, f16* __restrict__ ctx) {
  int id = blockIdx.x;
  int sw = ((id & 7) << 10) + (id >> 3);  // XCD-bijective swizzle (8192 % 8 == 0)
  int bh = sw >> 6;
  int q0 = (sw & 63) << 4;
  int b = bh >> 4, h = bh & 15;
  int tid = threadIdx.x;
  int w = tid >> 6, lane = tid & 63, c = lane & 15, g = lane >> 4;

  __shared__ float qrel_s[16 * 68];
  __shared__ float rmax[4][16], rsum[4][16], rlo[4][16], rhi[4][16];
  __shared__ float lo_s[16], hi_s[16];
  __shared__ f16 P_lds[1024 * 18];  // [k][q], stride 18 f16 = 36 B (q slots 16,17 unused)
  __shared__ f16 rel_s[65 * 64];

  const f16* Qb = Q + ((size_t)bh << 16);
  const f16* Kb = Km + ((size_t)bh << 16);
  const f16* Vtb = Vt + ((size_t)bh << 16);

  for (int i = tid; i < 65 * 64; i += 256) rel_s[i] = rel[i];

  f16x8 aq0 = *(const f16x8*)(Qb + ((q0 + c) << 6) + (g << 3));
  f16x8 aq1 = *(const f16x8*)(Qb + ((q0 + c) << 6) + 32 + (g << 3));

  if (w == 0) {  // qrel[q,t] = Q[q,:] . rel_emb[t,:]
#pragma unroll
    for (int tf = 0; tf < 5; tf++) {
      int t = tf * 16 + c;
      int tc = (t < 65) ? t : 0;
      f32x4 ar = {};
      f16x8 b0 = *(const f16x8*)(rel + (tc << 6) + (g << 3));
      f16x8 b1 = *(const f16x8*)(rel + (tc << 6) + 32 + (g << 3));
      MFMA16(ar, aq0, b0);
      MFMA16(ar, aq1, b1);
      if (t < 65) {
#pragma unroll
        for (int r = 0; r < 4; r++) qrel_s[((g << 2) + r) * 68 + t] = ar[r];
      }
    }
  }
  __syncthreads();

  float s[16][4];
  int kbase = w << 8;
#pragma unroll
  for (int f = 0; f < 16; f++) {
    int kcol = kbase + (f << 4) + c;
    f32x4 a4 = {};
    f16x8 b0 = *(const f16x8*)(Kb + (kcol << 6) + (g << 3));
    f16x8 b1 = *(const f16x8*)(Kb + (kcol << 6) + 32 + (g << 3));
    MFMA16(a4, aq0, b0);
    MFMA16(a4, aq1, b1);
#pragma unroll
    for (int r = 0; r < 4; r++) {
      int rowl = (g << 2) + r;
      int d = kcol - (q0 + rowl);
      int t = (d < -32 ? -32 : (d > 32 ? 32 : d)) + 32;
      s[f][r] = a4[r] + qrel_s[rowl * 68 + t];
    }
  }

  float m[4] = {-3.0e38f, -3.0e38f, -3.0e38f, -3.0e38f};
#pragma unroll
  for (int f = 0; f < 16; f++)
#pragma unroll
    for (int r = 0; r < 4; r++) m[r] = fmaxf(m[r], s[f][r]);
#pragma unroll
  for (int mk = 1; mk <= 8; mk <<= 1)
#pragma unroll
    for (int r = 0; r < 4; r++) m[r] = fmaxf(m[r], __shfl_xor(m[r], mk, 64));
  if (c == 0) {
#pragma unroll
    for (int r = 0; r < 4; r++) rmax[w][(g << 2) + r] = m[r];
  }
  __syncthreads();
  float gm[4];
#pragma unroll
  for (int r = 0; r < 4; r++) {
    int rowl = (g << 2) + r;
    gm[r] = fmaxf(fmaxf(rmax[0][rowl], rmax[1][rowl]), fmaxf(rmax[2][rowl], rmax[3][rowl]));
  }
  float sum[4] = {0, 0, 0, 0}, lo[4] = {0, 0, 0, 0}, hi[4] = {0, 0, 0, 0};
#pragma unroll
  for (int f = 0; f < 16; f++)
#pragma unroll
    for (int r = 0; r < 4; r++) {
      float p = __expf(s[f][r] - gm[r]);
      s[f][r] = p;
      sum[r] += p;
      int d = (kbase + (f << 4) + c) - (q0 + (g << 2) + r);
      if (d <= -32) lo[r] += p;
      if (d >= 32) hi[r] += p;
    }
#pragma unroll
  for (int mk = 1; mk <= 8; mk <<= 1)
#pragma unroll
    for (int r = 0; r < 4; r++) {
      sum[r] += __shfl_xor(sum[r], mk, 64);
      lo[r] += __shfl_xor(lo[r], mk, 64);
      hi[r] += __shfl_xor(hi[r], mk, 64);
    }
  if (c == 0) {
#pragma unroll
    for (int r = 0; r < 4; r++) {
      int rowl = (g << 2) + r;
      rsum[w][rowl] = sum[r];
      rlo[w][rowl] = lo[r];
      rhi[w][rowl] = hi[r];
    }
  }
  __syncthreads();
  float inv[4];
#pragma unroll
  for (int r = 0; r < 4; r++) {
    int rowl = (g << 2) + r;
    float tot = rsum[0][rowl] + rsum[1][rowl] + rsum[2][rowl] + rsum[3][rowl];
    inv[r] = 1.0f / tot;
  }
  if (w == 0 && c == 0) {
#pragma unroll
    for (int r = 0; r < 4; r++) {
      int rowl = (g << 2) + r;
      float l4 = rlo[0][rowl] + rlo[1][rowl] + rlo[2][rowl] + rlo[3][rowl];
      float h4 = rhi[0][rowl] + rhi[1][rowl] + rhi[2][rowl] + rhi[3][rowl];
      lo_s[rowl] = l4 * inv[r];
      hi_s[rowl] = h4 * inv[r];
    }
  }

  // attn write (f32, required output) + P into k-major LDS (f16x2 aligned writes)
  float* ab = attn + ((size_t)bh << 20);
#pragma unroll
  for (int f = 0; f < 16; f++) {
    int k = kbase + (f << 4) + c;
    f16 ph[4];
#pragma unroll
    for (int r = 0; r < 4; r++) {
      float p = s[f][r] * inv[r];
      ab[((size_t)(q0 + (g << 2) + r) << 10) | (size_t)k] = p;
      ph[r] = (f16)p;
    }
    int koff = k * 18 + (g << 2);
    f16x2 p01 = {ph[0], ph[1]};
    f16x2 p23 = {ph[2], ph[3]};
    *(f16x2*)(P_lds + koff) = p01;
    *(f16x2*)(P_lds + koff + 2) = p23;
  }
  __syncthreads();

  // PV as ctx^T = V^T @ P^T. Wave w owns d-slice [16w, 16w+16).
  // A-frag: V^T[d=16w+c][k] direct f16x8 global load (L2-hot).
  // B-frag: P_lds[k][c] scalar reads, conflict-free by stride-18 layout.
  f32x4 pv0 = {}, pv1 = {};
  const f16* vrow = Vtb + (size_t)((w << 4) + c) * 1024;
#pragma unroll 4
  for (int kk = 0; kk < 1024; kk += 64) {
    f16x8 aV0 = *(const f16x8*)(vrow + kk + (g << 3));
    f16x8 bP0;
#pragma unroll
    for (int j = 0; j < 8; j++) bP0[j] = P_lds[(kk + (g << 3) + j) * 18 + c];
    MFMA16(pv0, aV0, bP0);
    f16x8 aV1 = *(const f16x8*)(vrow + kk + 32 + (g << 3));
    f16x8 bP1;
#pragma unroll
    for (int j = 0; j < 8; j++) bP1[j] = P_lds[(kk + 32 + (g << 3) + j) * 18 + c];
    MFMA16(pv1, aV1, bP1);
  }

  // epilogue: lane holds ctx^T[d = 16w + (g<<2)+r][q = q0 + c]
  int qg = q0 + c;
  float cval[4];
#pragma unroll
  for (int r = 0; r < 4; r++) {
    int d = (w << 4) + (g << 2) + r;
    cval[r] = pv0[r] + pv1[r] + lo_s[c] * (float)rel_s[d] + hi_s[c] * (float)rel_s[64 * 64 + d];
  }
  for (int t = 1; t < 64; t++) {
    int k = qg + t - 32;
    if (k >= 0 && k < 1024) {
      float pk = (float)P_lds[k * 18 + c];
#pragma unroll
      for (int r = 0; r < 4; r++) {
        int d = (w << 4) + (g << 2) + r;
        cval[r] += pk * (float)rel_s[t * 64 + d];
      }
    }
  }

#pragma unroll
  for (int r = 0; r < 4; r++) {
    int d = (w << 4) + (g << 2) + r;
    ctx[(((size_t)(b << 10) + qg) << 10) + (h << 6) + d] = (f16)cval[r];
  }
}

extern "C" void kernel_launch(void* const* d_in, const int* in_sizes, int n_in, void* d_out, int out_size,
                              void* d_ws, size_t ws_size, hipStream_t stream) {
  const float* key = (const float*)d_in[0];
  const float* value = (const float*)d_in[1];
  const float* query = (const float*)d_in[2];
  const float* Wq = (const float*)d_in[3];
  const float* bq = (const float*)d_in[4];
  const float* Wk = (const float*)d_in[5];
  const float* bk = (const float*)d_in[6];
  const float* Wv = (const float*)d_in[7];
  const float* bv = (const float*)d_in[8];
  const float* Wo = (const float*)d_in[9];
  const float* bo = (const float*)d_in[10];
  const float* rel = (const float*)d_in[11];

  char* ws = (char*)d_ws;
  f16* Xf = (f16*)(ws);                  // 16 MB: f16 input staging (q/k/v); later ctx [B,L,D]
  f16* Qw = (f16*)(ws + (16u << 20));    // 16 MB: Q proj [B,H,L,64]
  f16* Kw = (f16*)(ws + (32u << 20));    // 16 MB: K proj [B,H,L,64]
  f16* Vw = (f16*)(ws + (48u << 20));    // 16 MB: V proj TRANSPOSED [B,H,64,L]
  f16* Wf = (f16*)(ws + (64u << 20));    // 2 MB: shared weight staging (stream-serialized)
  f16* relf = (f16*)(ws + (66u << 20));  // 8320 B
  // peak ws use: ~66.1 MB

  float* outp = (float*)d_out;
  float* attnp = outp + (size_t)8 * 1024 * 1024;  // attn (f32) starts at elem 8388608

  dim3 blk(256);
  const int n8x = (8 * 1024 * 1024) / 8;
  const int n8w = (1024 * 1024) / 8;
  const int n8r = (65 * 64) / 8;

  cvt_f32_f16_k<<<(n8r + 255) / 256, blk, 0, stream>>>(rel, relf, n8r);

  cvt_f32_f16_k<<<n8w / 256, blk, 0, stream>>>(Wq, Wf, n8w);
  cvt_f32_f16_k<<<n8x / 256, blk, 0, stream>>>(query, Xf, n8x);
  gemm_bt<1><<<512, blk, 0, stream>>>(Xf, Wf, bq, Qw, 8192, 1024, 1024, 0.125f);

  cvt_f32_f16_k<<<n8w / 256, blk, 0, stream>>>(Wk, Wf, n8w);
  cvt_f32_f16_k<<<n8x / 256, blk, 0, stream>>>(key, Xf, n8x);
  gemm_bt<1><<<512, blk, 0, stream>>>(Xf, Wf, bk, Kw, 8192, 1024, 1024, 1.0f);

  cvt_f32_f16_k<<<n8w / 256, blk, 0, stream>>>(Wv, Wf, n8w);
  cvt_f32_f16_k<<<n8x / 256, blk, 0, stream>>>(value, Xf, n8x);
  gemm_bt<2><<<512, blk, 0, stream>>>(Xf, Wf, bv, Vw, 8192, 1024, 1024, 1.0f);  // writes V^T

  attn_fused<<<8192, blk, 0, stream>>>(Qw, Kw, Vw, relf, attnp, Xf);  // ctx -> Xf

  cvt_f32_f16_k<<<n8w / 256, blk, 0, stream>>>(Wo, Wf, n8w);
  gemm_bt<0><<<512, blk, 0, stream>>>(Xf, Wf, bo, outp, 8192, 1024, 1024, 1.0f);
}

// Round 7
// 499.080 us; speedup vs baseline: 1.5553x; 1.0164x over previous
//
#include <hip/hip_runtime.h>

typedef unsigned short u16;
typedef _Float16 f16;
typedef __attribute__((ext_vector_type(8))) _Float16 f16x8;   // MFMA A/B operand (4 VGPRs)
typedef __attribute__((ext_vector_type(4))) _Float16 f16x4;
typedef __attribute__((ext_vector_type(2))) _Float16 f16x2;
typedef __attribute__((ext_vector_type(4))) float f32x4;

#define MFMA16(acc, a, b) acc = __builtin_amdgcn_mfma_f32_16x16x32_f16(a, b, acc, 0, 0, 0)

__device__ __forceinline__ void gl2lds16(const void* g, void* l) {
  __builtin_amdgcn_global_load_lds(
      (const __attribute__((address_space(1))) void*)g,
      (__attribute__((address_space(3))) void*)l, 16, 0, 0);
}

__device__ __forceinline__ void cvt8(const float* __restrict__ src, f16* __restrict__ dst, int i) {
  const float* p = src + (size_t)i * 8;
  f32x4 a = *(const f32x4*)p;
  f32x4 b = *(const f32x4*)(p + 4);
  f16x8 o;
#pragma unroll
  for (int j = 0; j < 4; j++) {
    o[j] = (f16)a[j];
    o[j + 4] = (f16)b[j];
  }
  *(f16x8*)(dst + (size_t)i * 8) = o;
}

// ---------------------------------------------------------------------------
// One-shot f32->f16 for all 4 weights + rel table (single launch).
// ---------------------------------------------------------------------------
__global__ __launch_bounds__(256) void cvt_all(const float* __restrict__ Wq, const float* __restrict__ Wk,
                                               const float* __restrict__ Wv, const float* __restrict__ Wo,
                                               const float* __restrict__ rel, f16* __restrict__ f0,
                                               f16* __restrict__ f1, f16* __restrict__ f2,
                                               f16* __restrict__ f3, f16* __restrict__ fr) {
  const int NW = 131072;  // (1024*1024)/8
  int i = blockIdx.x * 256 + threadIdx.x;
  if (i < NW) cvt8(Wq, f0, i);
  else if (i < 2 * NW) cvt8(Wk, f1, i - NW);
  else if (i < 3 * NW) cvt8(Wv, f2, i - 2 * NW);
  else if (i < 4 * NW) cvt8(Wo, f3, i - 3 * NW);
  else if (i < 4 * NW + 520) cvt8(rel, fr, i - 4 * NW);
}

// ---------------------------------------------------------------------------
// Fused QKV projection GEMM: 3 x (8192x1024x1024), A = raw f32 activations
// (converted in-staging: global f32x4 -> f16x8 -> ds_write_b128), W = f16.
// which = bid>>9 selects {query,key,value}. Q scaled 1/8. Outputs:
//   which 0/1 -> f16 [B,H,L,64]; which 2 -> f16 [B,H,64,L] (V^T).
// ---------------------------------------------------------------------------
__global__ __launch_bounds__(256) void gemm_qkv(const float* __restrict__ Aq, const float* __restrict__ Ak,
                                                const float* __restrict__ Av, const f16* __restrict__ W0,
                                                const f16* __restrict__ W1, const f16* __restrict__ W2,
                                                const float* __restrict__ b0, const float* __restrict__ b1,
                                                const float* __restrict__ b2, f16* __restrict__ O0,
                                                f16* __restrict__ O1, f16* __restrict__ O2) {
  int id = blockIdx.x;
  int which = id >> 9;
  int iid = id & 511;
  const float* A = (which == 0) ? Aq : (which == 1) ? Ak : Av;
  const f16* Wt = (which == 0) ? W0 : (which == 1) ? W1 : W2;
  const float* bias = (which == 0) ? b0 : (which == 1) ? b1 : b2;
  f16* out = (which == 0) ? O0 : (which == 1) ? O1 : O2;
  float scale = (which == 0) ? 0.125f : 1.0f;

  int m0 = (iid >> 3) << 7;
  int n0 = (iid & 7) << 7;
  int tid = threadIdx.x;
  int w = tid >> 6, lane = tid & 63, c = lane & 15, g = lane >> 4;
  int wm = (w >> 1) << 6, wn = (w & 1) << 6;

  __shared__ f16 As[128 * 32];
  __shared__ f16 Bs[128 * 32];

  f32x4 acc[4][4] = {};
  int ci0 = tid, ci1 = tid + 256;
  int r0 = ci0 >> 2, ks0 = (ci0 & 3) << 3;
  int r1 = ci1 >> 2, ks1 = (ci1 & 3) << 3;

  for (int k0 = 0; k0 < 1024; k0 += 32) {
    __syncthreads();
    gl2lds16(Wt + (size_t)(n0 + (ci0 >> 2)) * 1024 + k0 + ((ci0 & 3) << 3), Bs + w * 512);
    gl2lds16(Wt + (size_t)(n0 + (ci1 >> 2)) * 1024 + k0 + ((ci1 & 3) << 3), Bs + w * 512 + 2048);
    {
      const float* ap0 = A + (size_t)(m0 + r0) * 1024 + k0 + ks0;
      const float* ap1 = A + (size_t)(m0 + r1) * 1024 + k0 + ks1;
      f32x4 x0 = *(const f32x4*)ap0, x1 = *(const f32x4*)(ap0 + 4);
      f32x4 y0 = *(const f32x4*)ap1, y1 = *(const f32x4*)(ap1 + 4);
      f16x8 h0, h1;
#pragma unroll
      for (int j = 0; j < 4; j++) {
        h0[j] = (f16)x0[j];
        h0[j + 4] = (f16)x1[j];
        h1[j] = (f16)y0[j];
        h1[j + 4] = (f16)y1[j];
      }
      *(f16x8*)(As + (r0 << 5) + ks0) = h0;
      *(f16x8*)(As + (r1 << 5) + ks1) = h1;
    }
    __syncthreads();
    f16x8 af[4], bf[4];
#pragma unroll
    for (int mf = 0; mf < 4; mf++) af[mf] = *(const f16x8*)(As + ((wm + mf * 16 + c) << 5) + (g << 3));
#pragma unroll
    for (int nf = 0; nf < 4; nf++) bf[nf] = *(const f16x8*)(Bs + ((wn + nf * 16 + c) << 5) + (g << 3));
#pragma unroll
    for (int mf = 0; mf < 4; mf++)
#pragma unroll
      for (int nf = 0; nf < 4; nf++) MFMA16(acc[mf][nf], af[mf], bf[nf]);
  }

#pragma unroll
  for (int mf = 0; mf < 4; mf++)
#pragma unroll
    for (int nf = 0; nf < 4; nf++) {
      int row0 = m0 + wm + mf * 16 + (g << 2);
      int col = n0 + wn + nf * 16 + c;
      if (which == 2) {  // V^T: [bh][d=col&63][l=row]
        f16x4 vv;
#pragma unroll
        for (int r = 0; r < 4; r++) vv[r] = (f16)(acc[mf][nf][r] + bias[col]);
        size_t idx = (size_t)((row0 >> 10) * 16 + (col >> 6)) * 65536 + (size_t)(col & 63) * 1024 + (row0 & 1023);
        *(f16x4*)(out + idx) = vv;
      } else {  // [bh][l=row][d=col&63]
#pragma unroll
        for (int r = 0; r < 4; r++) {
          int row = row0 + r;
          size_t idx = (size_t)((row >> 10) * 16 + (col >> 6)) * 65536 + ((row & 1023) << 6) + (col & 63);
          out[idx] = (f16)((acc[mf][nf][r] + bias[col]) * scale);
        }
      }
    }
}

// ---------------------------------------------------------------------------
// Output GEMM: out[M,N] f32 = ctx[M,K] f16 @ Wo[N,K]^T + bo. (m97 structure)
// ---------------------------------------------------------------------------
__global__ __launch_bounds__(256) void gemm_out(const f16* __restrict__ A, const f16* __restrict__ Wt,
                                                const float* __restrict__ bias, float* __restrict__ out) {
  int id = blockIdx.x;
  int m0 = (id >> 3) << 7;
  int n0 = (id & 7) << 7;
  int tid = threadIdx.x;
  int w = tid >> 6, lane = tid & 63, c = lane & 15, g = lane >> 4;
  int wm = (w >> 1) << 6, wn = (w & 1) << 6;

  __shared__ f16 As[128 * 32];
  __shared__ f16 Bs[128 * 32];

  f32x4 acc[4][4] = {};
  int ci0 = tid, ci1 = tid + 256;

  for (int k0 = 0; k0 < 1024; k0 += 32) {
    __syncthreads();
    gl2lds16(A + (size_t)(m0 + (ci0 >> 2)) * 1024 + k0 + ((ci0 & 3) << 3), As + w * 512);
    gl2lds16(A + (size_t)(m0 + (ci1 >> 2)) * 1024 + k0 + ((ci1 & 3) << 3), As + w * 512 + 2048);
    gl2lds16(Wt + (size_t)(n0 + (ci0 >> 2)) * 1024 + k0 + ((ci0 & 3) << 3), Bs + w * 512);
    gl2lds16(Wt + (size_t)(n0 + (ci1 >> 2)) * 1024 + k0 + ((ci1 & 3) << 3), Bs + w * 512 + 2048);
    __syncthreads();
    f16x8 af[4], bf[4];
#pragma unroll
    for (int mf = 0; mf < 4; mf++) af[mf] = *(const f16x8*)(As + ((wm + mf * 16 + c) << 5) + (g << 3));
#pragma unroll
    for (int nf = 0; nf < 4; nf++) bf[nf] = *(const f16x8*)(Bs + ((wn + nf * 16 + c) << 5) + (g << 3));
#pragma unroll
    for (int mf = 0; mf < 4; mf++)
#pragma unroll
      for (int nf = 0; nf < 4; nf++) MFMA16(acc[mf][nf], af[mf], bf[nf]);
  }

#pragma unroll
  for (int mf = 0; mf < 4; mf++)
#pragma unroll
    for (int nf = 0; nf < 4; nf++)
#pragma unroll
      for (int r = 0; r < 4; r++) {
        int row = m0 + wm + mf * 16 + (g << 2) + r;
        int col = n0 + wn + nf * 16 + c;
        out[(size_t)row * 1024 + col] = acc[mf][nf][r] + bias[col];
      }
}

// ---------------------------------------------------------------------------
// FUSED scores + softmax + attn-write + PV + rel-values -> ctx. (round-6 form)
// ---------------------------------------------------------------------------
__global__ __launch_bounds__(256) void attn_fused(const f16* __restrict__ Q, const f16* __restrict__ Km,
                                                  const f16* __restrict__ Vt, const f16* __restrict__ rel,
                                                  float* __restrict__ attn, f16* __restrict__ ctx) {
  int id = blockIdx.x;
  int sw = ((id & 7) << 10) + (id >> 3);  // XCD-bijective swizzle (8192 % 8 == 0)
  int bh = sw >> 6;
  int q0 = (sw & 63) << 4;
  int b = bh >> 4, h = bh & 15;
  int tid = threadIdx.x;
  int w = tid >> 6, lane = tid & 63, c = lane & 15, g = lane >> 4;

  __shared__ float qrel_s[16 * 68];
  __shared__ float rmax[4][16], rsum[4][16], rlo[4][16], rhi[4][16];
  __shared__ float lo_s[16], hi_s[16];
  __shared__ f16 P_lds[1024 * 18];  // [k][q], stride 18 f16 (q slots 16,17 unused)
  __shared__ f16 rel_s[65 * 64];

  const f16* Qb = Q + ((size_t)bh << 16);
  const f16* Kb = Km + ((size_t)bh << 16);
  const f16* Vtb = Vt + ((size_t)bh << 16);

  for (int i = tid; i < 65 * 64; i += 256) rel_s[i] = rel[i];

  f16x8 aq0 = *(const f16x8*)(Qb + ((q0 + c) << 6) + (g << 3));
  f16x8 aq1 = *(const f16x8*)(Qb + ((q0 + c) << 6) + 32 + (g << 3));

  if (w == 0) {  // qrel[q,t] = Q[q,:] . rel_emb[t,:]
#pragma unroll
    for (int tf = 0; tf < 5; tf++) {
      int t = tf * 16 + c;
      int tc = (t < 65) ? t : 0;
      f32x4 ar = {};
      f16x8 b0 = *(const f16x8*)(rel + (tc << 6) + (g << 3));
      f16x8 b1 = *(const f16x8*)(rel + (tc << 6) + 32 + (g << 3));
      MFMA16(ar, aq0, b0);
      MFMA16(ar, aq1, b1);
      if (t < 65) {
#pragma unroll
        for (int r = 0; r < 4; r++) qrel_s[((g << 2) + r) * 68 + t] = ar[r];
      }
    }
  }
  __syncthreads();

  float s[16][4];
  int kbase = w << 8;
#pragma unroll
  for (int f = 0; f < 16; f++) {
    int kcol = kbase + (f << 4) + c;
    f32x4 a4 = {};
    f16x8 b0 = *(const f16x8*)(Kb + (kcol << 6) + (g << 3));
    f16x8 b1 = *(const f16x8*)(Kb + (kcol << 6) + 32 + (g << 3));
    MFMA16(a4, aq0, b0);
    MFMA16(a4, aq1, b1);
#pragma unroll
    for (int r = 0; r < 4; r++) {
      int rowl = (g << 2) + r;
      int d = kcol - (q0 + rowl);
      int t = (d < -32 ? -32 : (d > 32 ? 32 : d)) + 32;
      s[f][r] = a4[r] + qrel_s[rowl * 68 + t];
    }
  }

  float m[4] = {-3.0e38f, -3.0e38f, -3.0e38f, -3.0e38f};
#pragma unroll
  for (int f = 0; f < 16; f++)
#pragma unroll
    for (int r = 0; r < 4; r++) m[r] = fmaxf(m[r], s[f][r]);
#pragma unroll
  for (int mk = 1; mk <= 8; mk <<= 1)
#pragma unroll
    for (int r = 0; r < 4; r++) m[r] = fmaxf(m[r], __shfl_xor(m[r], mk, 64));
  if (c == 0) {
#pragma unroll
    for (int r = 0; r < 4; r++) rmax[w][(g << 2) + r] = m[r];
  }
  __syncthreads();
  float gm[4];
#pragma unroll
  for (int r = 0; r < 4; r++) {
    int rowl = (g << 2) + r;
    gm[r] = fmaxf(fmaxf(rmax[0][rowl], rmax[1][rowl]), fmaxf(rmax[2][rowl], rmax[3][rowl]));
  }
  float sum[4] = {0, 0, 0, 0}, lo[4] = {0, 0, 0, 0}, hi[4] = {0, 0, 0, 0};
#pragma unroll
  for (int f = 0; f < 16; f++)
#pragma unroll
    for (int r = 0; r < 4; r++) {
      float p = __expf(s[f][r] - gm[r]);
      s[f][r] = p;
      sum[r] += p;
      int d = (kbase + (f << 4) + c) - (q0 + (g << 2) + r);
      if (d <= -32) lo[r] += p;
      if (d >= 32) hi[r] += p;
    }
#pragma unroll
  for (int mk = 1; mk <= 8; mk <<= 1)
#pragma unroll
    for (int r = 0; r < 4; r++) {
      sum[r] += __shfl_xor(sum[r], mk, 64);
      lo[r] += __shfl_xor(lo[r], mk, 64);
      hi[r] += __shfl_xor(hi[r], mk, 64);
    }
  if (c == 0) {
#pragma unroll
    for (int r = 0; r < 4; r++) {
      int rowl = (g << 2) + r;
      rsum[w][rowl] = sum[r];
      rlo[w][rowl] = lo[r];
      rhi[w][rowl] = hi[r];
    }
  }
  __syncthreads();
  float inv[4];
#pragma unroll
  for (int r = 0; r < 4; r++) {
    int rowl = (g << 2) + r;
    float tot = rsum[0][rowl] + rsum[1][rowl] + rsum[2][rowl] + rsum[3][rowl];
    inv[r] = 1.0f / tot;
  }
  if (w == 0 && c == 0) {
#pragma unroll
    for (int r = 0; r < 4; r++) {
      int rowl = (g << 2) + r;
      float l4 = rlo[0][rowl] + rlo[1][rowl] + rlo[2][rowl] + rlo[3][rowl];
      float h4 = rhi[0][rowl] + rhi[1][rowl] + rhi[2][rowl] + rhi[3][rowl];
      lo_s[rowl] = l4 * inv[r];
      hi_s[rowl] = h4 * inv[r];
    }
  }

  // attn write (f32, required output) + P into k-major LDS (f16x2 aligned writes)
  float* ab = attn + ((size_t)bh << 20);
#pragma unroll
  for (int f = 0; f < 16; f++) {
    int k = kbase + (f << 4) + c;
    f16 ph[4];
#pragma unroll
    for (int r = 0; r < 4; r++) {
      float p = s[f][r] * inv[r];
      ab[((size_t)(q0 + (g << 2) + r) << 10) | (size_t)k] = p;
      ph[r] = (f16)p;
    }
    int koff = k * 18 + (g << 2);
    f16x2 p01 = {ph[0], ph[1]};
    f16x2 p23 = {ph[2], ph[3]};
    *(f16x2*)(P_lds + koff) = p01;
    *(f16x2*)(P_lds + koff + 2) = p23;
  }
  __syncthreads();

  // PV as ctx^T = V^T @ P^T; V^T frags direct from global (L2-hot).
  f32x4 pv0 = {}, pv1 = {};
  const f16* vrow = Vtb + (size_t)((w << 4) + c) * 1024;
#pragma unroll 4
  for (int kk = 0; kk < 1024; kk += 64) {
    f16x8 aV0 = *(const f16x8*)(vrow + kk + (g << 3));
    f16x8 bP0;
#pragma unroll
    for (int j = 0; j < 8; j++) bP0[j] = P_lds[(kk + (g << 3) + j) * 18 + c];
    MFMA16(pv0, aV0, bP0);
    f16x8 aV1 = *(const f16x8*)(vrow + kk + 32 + (g << 3));
    f16x8 bP1;
#pragma unroll
    for (int j = 0; j < 8; j++) bP1[j] = P_lds[(kk + 32 + (g << 3) + j) * 18 + c];
    MFMA16(pv1, aV1, bP1);
  }

  // epilogue: lane holds ctx^T[d = 16w + (g<<2)+r][q = q0 + c]
  int qg = q0 + c;
  float cval[4];
#pragma unroll
  for (int r = 0; r < 4; r++) {
    int d = (w << 4) + (g << 2) + r;
    cval[r] = pv0[r] + pv1[r] + lo_s[c] * (float)rel_s[d] + hi_s[c] * (float)rel_s[64 * 64 + d];
  }
  for (int t = 1; t < 64; t++) {
    int k = qg + t - 32;
    if (k >= 0 && k < 1024) {
      float pk = (float)P_lds[k * 18 + c];
#pragma unroll
      for (int r = 0; r < 4; r++) {
        int d = (w << 4) + (g << 2) + r;
        cval[r] += pk * (float)rel_s[t * 64 + d];
      }
    }
  }

#pragma unroll
  for (int r = 0; r < 4; r++) {
    int d = (w << 4) + (g << 2) + r;
    ctx[(((size_t)(b << 10) + qg) << 10) + (h << 6) + d] = (f16)cval[r];
  }
}

extern "C" void kernel_launch(void* const* d_in, const int* in_sizes, int n_in, void* d_out, int out_size,
                              void* d_ws, size_t ws_size, hipStream_t stream) {
  const float* key = (const float*)d_in[0];
  const float* value = (const float*)d_in[1];
  const float* query = (const float*)d_in[2];
  const float* Wq = (const float*)d_in[3];
  const float* bq = (const float*)d_in[4];
  const float* Wk = (const float*)d_in[5];
  const float* bk = (const float*)d_in[6];
  const float* Wv = (const float*)d_in[7];
  const float* bv = (const float*)d_in[8];
  const float* Wo = (const float*)d_in[9];
  const float* bo = (const float*)d_in[10];
  const float* rel = (const float*)d_in[11];

  char* ws = (char*)d_ws;
  // ctx region [0,16M) doubles as Wf0/Wf1/Wf2 staging during projections
  // (attn_fused overwrites it with ctx only after gemm_qkv is done).
  f16* ctx = (f16*)(ws);
  f16* Wf0 = (f16*)(ws);
  f16* Wf1 = (f16*)(ws + (2u << 20));
  f16* Wf2 = (f16*)(ws + (4u << 20));
  f16* Qw = (f16*)(ws + (16u << 20));    // Q proj [B,H,L,64]
  f16* Kw = (f16*)(ws + (32u << 20));    // K proj [B,H,L,64]
  f16* Vw = (f16*)(ws + (48u << 20));    // V proj TRANSPOSED [B,H,64,L]
  f16* Wf3 = (f16*)(ws + (64u << 20));   // Wo f16 (must survive attn_fused)
  f16* relf = (f16*)(ws + (66u << 20));  // 8320 B
  // peak ws use: ~66.01 MB (validated level)

  float* outp = (float*)d_out;
  float* attnp = outp + (size_t)8 * 1024 * 1024;  // attn (f32) at elem 8388608

  dim3 blk(256);
  cvt_all<<<2051, blk, 0, stream>>>(Wq, Wk, Wv, Wo, rel, Wf0, Wf1, Wf2, Wf3, relf);
  gemm_qkv<<<1536, blk, 0, stream>>>(query, key, value, Wf0, Wf1, Wf2, bq, bk, bv, Qw, Kw, Vw);
  attn_fused<<<8192, blk, 0, stream>>>(Qw, Kw, Vw, relf, attnp, ctx);
  gemm_out<<<512, blk, 0, stream>>>(ctx, Wf3, bo, outp);
}